// Round 16
// baseline (416.183 us; speedup 1.0000x reference)
//
#include <hip/hip_runtime.h>
#include <hip/hip_bf16.h>

// ---------- types & helpers ----------
typedef __attribute__((ext_vector_type(4))) float f32x4;
typedef __attribute__((ext_vector_type(8))) short s16x8;

__device__ __forceinline__ unsigned short f2bf(float f) {
    __hip_bfloat16 h = __float2bfloat16(f);
    return __builtin_bit_cast(unsigned short, h);
}
__device__ __forceinline__ float bf2f(unsigned short u) {
    return __builtin_bit_cast(float, ((unsigned)u) << 16);
}
__device__ __forceinline__ float2 bfpair(unsigned u) {
    float2 r;
    r.x = __builtin_bit_cast(float, u << 16);
    r.y = __builtin_bit_cast(float, u & 0xffff0000u);
    return r;
}
__device__ __forceinline__ void gload_lds16(const void* g, void* l) {
    __builtin_amdgcn_global_load_lds(
        (const __attribute__((address_space(1))) void*)g,
        (__attribute__((address_space(3))) void*)l, 16, 0, 0);
}
__device__ __forceinline__ float gelu_tanh(float x) {
    const float y = 0.7978845608028654f * (x + 0.044715f * x * x * x);
    const float t = __expf(-2.f * fabsf(y));
    const float th = (1.f - t) / (1.f + t);
    return 0.5f * x * (1.f + copysignf(th, y));
}

// ---------- fused fp32->bf16 convert + transpose ----------
__global__ __launch_bounds__(256)
void k_cvt_tr(const float* __restrict__ in, unsigned short* __restrict__ XBF,
              unsigned short* __restrict__ XT) {
    __shared__ __align__(16) unsigned short tile[64 * 64];
    const int t  = threadIdx.x;
    const int c0 = blockIdx.x * 64;
    const int ty = blockIdx.y;
    const long tokg = (long)ty * 64;
    const int cq = t & 15, r0 = t >> 4;
#pragma unroll
    for (int p = 0; p < 4; ++p) {
        const int tok = r0 + p * 16;
        const float4 v = *(const float4*)(in + (tokg + tok) * 512 + c0 + cq * 4);
        union { unsigned short h[4]; uint2 u; } pk;
        pk.h[0] = f2bf(v.x); pk.h[1] = f2bf(v.y); pk.h[2] = f2bf(v.z); pk.h[3] = f2bf(v.w);
        *(uint2*)(XBF + (tokg + tok) * 512 + c0 + cq * 4) = pk.u;
        const int T = tok >> 3, i = tok & 7;
#pragma unroll
        for (int j = 0; j < 4; ++j) {
            const int c = cq * 4 + j;
            tile[c * 64 + ((T ^ (c & 7)) * 8 + i)] = pk.h[j];
        }
    }
    __syncthreads();
    const int b  = ty >> 8;
    const long tb = (long)(ty & 255) * 64;
    const int T2 = t & 7;
#pragma unroll
    for (int q = 0; q < 2; ++q) {
        const int c = (t >> 3) + q * 32;
        const uint4 v = *(const uint4*)&tile[c * 64 + ((T2 ^ (c & 7)) * 8)];
        *(uint4*)(XT + ((long)(b * 512 + c0 + c)) * 16384 + tb + T2 * 8) = v;
    }
}

// ---------- build [WqT; WkT; WvT; WpT] bf16 [2048][512] via LDS 32x32 transpose ----------
__global__ __launch_bounds__(256)
void k_build_wcat(const float* __restrict__ Wq, const float* __restrict__ Wk,
                  const float* __restrict__ Wv, const float* __restrict__ Wp,
                  unsigned short* __restrict__ WcatT) {
    __shared__ float t[32][33];
    const int k0 = blockIdx.x * 32;
    const int j0 = blockIdx.y * 32;
    const float* src = (j0 < 512) ? Wq : (j0 < 1024 ? Wk : (j0 < 1536 ? Wv : Wp));
    const int jc0 = j0 & 511;
    const int r = threadIdx.x >> 5, c = threadIdx.x & 31;
#pragma unroll
    for (int rr = 0; rr < 4; ++rr) {
        const int k = k0 + r + rr * 8;
        t[c][r + rr * 8] = src[(long)k * 512 + jc0 + c];
    }
    __syncthreads();
#pragma unroll
    for (int rr = 0; rr < 4; ++rr) {
        const int j = j0 + r + rr * 8;
        WcatT[(long)j * 512 + k0 + c] = f2bf(t[r + rr * 8][c]);
    }
}

// ---------- MFMA bf16 GEMM 128x128 (m97-style): C[M,N] = A[M,K] * B[N,K]^T ----------
#define BM 128
#define BN 128
#define BK 64

template<int OUT_BF16, int BIAS, int ADDC>
__global__ __launch_bounds__(256, 4)
void gemm_mfma(const unsigned short* __restrict__ A, const unsigned short* __restrict__ B,
               void* __restrict__ C_, const float* __restrict__ bias,
               const unsigned short* __restrict__ addc,
               int lda, int ldb, int ldc, int K, long sA, long sB, long sC) {
    __shared__ __align__(16) unsigned short sm[BM * BK * 2];   // As | Bs; reused as C staging
    unsigned short* As = sm;
    unsigned short* Bs = sm + BM * BK;

    const int tid  = threadIdx.x;
    const int wave = tid >> 6;
    const int lane = tid & 63;
    const int wm = wave >> 1, wn = wave & 1;

    // XCD swizzle: consecutive-on-XCD blocks share the A panel
    const int nx = gridDim.x, ny = gridDim.y;
    const int nwg = nx * ny * gridDim.z;
    int lid = blockIdx.x + nx * (blockIdx.y + ny * blockIdx.z);
    lid = (lid & 7) * (nwg >> 3) + (lid >> 3);
    const int bxi = lid % nx;
    const int rest = lid / nx;
    const int byi = rest % ny;
    const long bz = rest / ny;
    const int bm0 = byi * BM;
    const int bn0 = bxi * BN;
    A += bz * sA;
    B += bz * sB;

    const int l15 = lane & 15;
    const int l4  = lane >> 4;

    f32x4 acc[4][4];
#pragma unroll
    for (int i = 0; i < 4; ++i)
#pragma unroll
        for (int j = 0; j < 4; ++j) acc[i][j] = (f32x4){0.f, 0.f, 0.f, 0.f};

    const int srow    = wave * 8 + (lane >> 3);
    const int schunk0 = lane & 7;
    const int arow_b  = wm * 64 + l15;
    const int brow_b  = wn * 64 + l15;

    const int nk = K / BK;
    for (int kt = 0; kt < nk; ++kt) {
        const int k0 = kt * BK;
#pragma unroll
        for (int i = 0; i < 4; ++i) {
            const int r  = i * 32 + srow;
            const int gc = schunk0 ^ (r & 7);
            gload_lds16(A + (long)(bm0 + r) * lda + (k0 + gc * 8), &As[(i * 32 + wave * 8) * BK]);
            gload_lds16(B + (long)(bn0 + r) * ldb + (k0 + gc * 8), &Bs[(i * 32 + wave * 8) * BK]);
        }
        __syncthreads();
        s16x8 af[4][2], bfr[4][2];
#pragma unroll
        for (int mi = 0; mi < 4; ++mi) {
            const int row = arow_b + mi * 16;
#pragma unroll
            for (int ki = 0; ki < 2; ++ki) {
                const int ch = (ki * 4 + l4) ^ (row & 7);
                af[mi][ki] = *(const s16x8*)&As[row * BK + ch * 8];
            }
        }
#pragma unroll
        for (int ni = 0; ni < 4; ++ni) {
            const int row = brow_b + ni * 16;
#pragma unroll
            for (int ki = 0; ki < 2; ++ki) {
                const int ch = (ki * 4 + l4) ^ (row & 7);
                bfr[ni][ki] = *(const s16x8*)&Bs[row * BK + ch * 8];
            }
        }
#pragma unroll
        for (int ki = 0; ki < 2; ++ki)
#pragma unroll
            for (int mi = 0; mi < 4; ++mi)
#pragma unroll
                for (int ni = 0; ni < 4; ++ni)
                    acc[mi][ni] = __builtin_amdgcn_mfma_f32_16x16x32_bf16(
                        af[mi][ki], bfr[ni][ki], acc[mi][ni], 0, 0, 0);
        __syncthreads();
    }

    // ---- staged epilogue: acc -> LDS -> wide coalesced stores ----
    if (OUT_BF16) {
        unsigned short* Cs = sm;   // [128][64] bf16 (16KB)
        unsigned short* C = (unsigned short*)C_ + bz * sC;
#pragma unroll
        for (int pass = 0; pass < 2; ++pass) {
            __syncthreads();
            if (wn == pass) {
#pragma unroll
                for (int mi = 0; mi < 4; ++mi)
#pragma unroll
                    for (int ni = 0; ni < 4; ++ni)
#pragma unroll
                        for (int j = 0; j < 4; ++j)
                            Cs[(wm * 64 + mi * 16 + l4 * 4 + j) * 64 + ni * 16 + l15] =
                                f2bf(acc[mi][ni][j]);
            }
            __syncthreads();
            const int colL = (tid & 7) * 8;
#pragma unroll
            for (int it = 0; it < 4; ++it) {
                const int row = it * 32 + (tid >> 3);
                const uint4 v = *(const uint4*)&Cs[row * 64 + colL];
                *(uint4*)&C[(long)(bm0 + row) * ldc + bn0 + pass * 64 + colL] = v;
            }
        }
    } else {
        float* Cs = (float*)sm;    // [128][64] f32 (32KB)
        float* C = (float*)C_ + bz * sC;
#pragma unroll
        for (int pass = 0; pass < 2; ++pass) {
            __syncthreads();
            if (wn == pass) {
#pragma unroll
                for (int mi = 0; mi < 4; ++mi)
#pragma unroll
                    for (int ni = 0; ni < 4; ++ni)
#pragma unroll
                        for (int j = 0; j < 4; ++j)
                            Cs[(wm * 64 + mi * 16 + l4 * 4 + j) * 64 + ni * 16 + l15] =
                                acc[mi][ni][j];
            }
            __syncthreads();
            const int colL = (tid & 15) * 4;
#pragma unroll
            for (int it = 0; it < 8; ++it) {
                const int row = it * 16 + (tid >> 4);
                f32x4 v = *(const f32x4*)&Cs[row * 64 + colL];
                const long gr = bm0 + row;
                const int gc = bn0 + pass * 64 + colL;
                if (BIAS) {
                    const float4 bv = *(const float4*)(bias + gc);
                    v[0] += bv.x; v[1] += bv.y; v[2] += bv.z; v[3] += bv.w;
                }
                if (ADDC) {
                    const uint2 a2 = *(const uint2*)(addc + bz * sC + gr * ldc + gc);
                    v[0] += bf2f((unsigned short)(a2.x & 0xffff));
                    v[1] += bf2f((unsigned short)(a2.x >> 16));
                    v[2] += bf2f((unsigned short)(a2.y & 0xffff));
                    v[3] += bf2f((unsigned short)(a2.y >> 16));
                }
                *(f32x4*)&C[gr * ldc + gc] = v;
            }
        }
    }
}

// ---------- Gram split-K, SYMMETRY-HALVED ----------
__global__ __launch_bounds__(256, 4)
void gemm_gram(const unsigned short* __restrict__ XT, float* __restrict__ P) {
    __shared__ __align__(16) unsigned short As[128 * 64];
    __shared__ __align__(16) unsigned short Bs[128 * 64];
    const int tid = threadIdx.x, wave = tid >> 6, lane = tid & 63;
    const int wm = wave >> 1, wn = wave & 1;
    const int p = blockIdx.x;               // 0..9
    int ti, tj;
    if (p < 4)      { ti = 0; tj = p; }
    else if (p < 7) { ti = 1; tj = p - 3; }
    else if (p < 9) { ti = 2; tj = p - 5; }
    else            { ti = 3; tj = 3; }
    const int bm0 = ti * 128, bn0 = tj * 128;
    const int z = blockIdx.y, b = z >> 3, chunk = z & 7;
    const unsigned short* A = XT + (long)b * 512 * 16384;
    const int l15 = lane & 15, l4 = lane >> 4;

    f32x4 acc[4][4];
#pragma unroll
    for (int i = 0; i < 4; ++i)
#pragma unroll
        for (int j = 0; j < 4; ++j) acc[i][j] = (f32x4){0.f, 0.f, 0.f, 0.f};

    const int srow = wave * 8 + (lane >> 3);
    const int sch  = lane & 7;
    const int arow_b = wm * 64 + l15;
    const int brow_b = wn * 64 + l15;

    for (int kt = 0; kt < 32; ++kt) {
        const long k0 = (long)chunk * 2048 + kt * 64;
#pragma unroll
        for (int i = 0; i < 4; ++i) {
            const int r  = i * 32 + srow;
            const int gc = sch ^ (r & 7);
            gload_lds16(A + (long)(bm0 + r) * 16384 + k0 + gc * 8, &As[(i * 32 + wave * 8) * 64]);
            gload_lds16(A + (long)(bn0 + r) * 16384 + k0 + gc * 8, &Bs[(i * 32 + wave * 8) * 64]);
        }
        __syncthreads();
        s16x8 af[4][2], bfr[4][2];
#pragma unroll
        for (int mi = 0; mi < 4; ++mi) {
            const int row = arow_b + mi * 16;
#pragma unroll
            for (int ki = 0; ki < 2; ++ki)
                af[mi][ki] = *(const s16x8*)&As[row * 64 + (((ki * 4 + l4) ^ (row & 7))) * 8];
        }
#pragma unroll
        for (int ni = 0; ni < 4; ++ni) {
            const int row = brow_b + ni * 16;
#pragma unroll
            for (int ki = 0; ki < 2; ++ki)
                bfr[ni][ki] = *(const s16x8*)&Bs[row * 64 + (((ki * 4 + l4) ^ (row & 7))) * 8];
        }
#pragma unroll
        for (int ki = 0; ki < 2; ++ki)
#pragma unroll
            for (int mi = 0; mi < 4; ++mi)
#pragma unroll
                for (int ni = 0; ni < 4; ++ni)
                    acc[mi][ni] = __builtin_amdgcn_mfma_f32_16x16x32_bf16(
                        af[mi][ki], bfr[ni][ki], acc[mi][ni], 0, 0, 0);
        __syncthreads();
    }

    const long zbase = (long)(b * 8 + chunk) * 16;
    float* Pb = P + (zbase + ti * 4 + tj) * 16384;
#pragma unroll
    for (int mi = 0; mi < 4; ++mi) {
        const int row0 = wm * 64 + mi * 16 + l4 * 4;
#pragma unroll
        for (int ni = 0; ni < 4; ++ni) {
            const int col = wn * 64 + ni * 16 + l15;
#pragma unroll
            for (int j = 0; j < 4; ++j)
                Pb[(row0 + j) * 128 + col] = acc[mi][ni][j];
        }
    }
    if (ti != tj) {   // mirror block
        float* Pt = P + (zbase + tj * 4 + ti) * 16384;
#pragma unroll
        for (int mi = 0; mi < 4; ++mi) {
            const int row0 = wm * 64 + mi * 16 + l4 * 4;
#pragma unroll
            for (int ni = 0; ni < 4; ++ni) {
                const int col = wn * 64 + ni * 16 + l15;
                *(f32x4*)&Pt[(long)col * 128 + row0] = acc[mi][ni];
            }
        }
    }
}

// ---------- reduce partials over chunks -> GB bf16 [4][512][512] ----------
__global__ void k_greduce(const float* __restrict__ P, unsigned* __restrict__ GB2) {
    const long idx = (long)blockIdx.x * 256 + threadIdx.x;
    const int b   = (int)(idx >> 17);
    const int rem = (int)(idx & 131071);
    const int c   = rem >> 8;
    const int cp0 = (rem & 255) * 2;
    const int tp  = (c >> 7) * 4 + (cp0 >> 7);
    const int e   = (c & 127) * 128 + (cp0 & 127);
    const float* Pp = P + ((long)(b * 8) * 16 + tp) * 16384 + e;
    float s0 = 0.f, s1 = 0.f;
#pragma unroll
    for (int ch = 0; ch < 8; ++ch) {
        const float2 v = *(const float2*)(Pp + (long)ch * 16 * 16384);
        s0 += v.x; s1 += v.y;
    }
    GB2[idx] = (unsigned)f2bf(s0) | ((unsigned)f2bf(s1) << 16);
}

// ---------- row-dots for sumsq (T12 layout: [b][1024][512]) ----------
__global__ void k_ssq(const unsigned short* __restrict__ WCT, const unsigned short* __restrict__ T12,
                      float* __restrict__ SSQ) {
    const int b = blockIdx.y;
    const int o = blockIdx.x * 256 + threadIdx.x;   // 0..1023
    const unsigned short* wrow = WCT + (long)o * 512;
    const unsigned short* trow = T12 + (long)b * 524288 + (long)o * 512;
    float s = 0.f;
    for (int c = 0; c < 512; c += 8) {
        const s16x8 w = *(const s16x8*)&wrow[c];
        const s16x8 v = *(const s16x8*)&trow[c];
#pragma unroll
        for (int j = 0; j < 8; ++j)
            s += bf2f((unsigned short)w[j]) * bf2f((unsigned short)v[j]);
    }
    SSQ[b * 1024 + o] = s;
}

// ---------- softmax -> block-diagonal bf16 matrix MBD[b][h*64+e][h*64+d] ----------
__global__ __launch_bounds__(256)
void k_softmax_bd(const float* __restrict__ attn, const float* __restrict__ sumsq,
                  const float* __restrict__ rescale, unsigned short* __restrict__ MBD) {
    __shared__ unsigned short TD[64 * 68];
    const int bh = blockIdx.x;
    const int b = bh >> 3, h = bh & 7;
    const int wave = threadIdx.x >> 6, e = threadIdx.x & 63;
    const float rs   = rescale[h];
    const float invq = rsqrtf(sumsq[b * 1024 + h * 64 + e]);
#pragma unroll 4
    for (int i = 0; i < 16; ++i) {
        const int d = wave * 16 + i;
        const float invk = rsqrtf(sumsq[b * 1024 + 512 + h * 64 + d]);
        const float v = attn[((long)b * 512 + h * 64 + d) * 512 + h * 64 + e] * invk * invq * rs;
        float mx = v;
#pragma unroll
        for (int off = 32; off >= 1; off >>= 1) mx = fmaxf(mx, __shfl_xor(mx, off));
        const float l = __expf(v - mx);
        float s = l;
#pragma unroll
        for (int off = 32; off >= 1; off >>= 1) s += __shfl_xor(s, off);
        TD[e * 68 + d] = f2bf(l / s);
    }
    __syncthreads();
    const int er = threadIdx.x >> 2, dc = (threadIdx.x & 3) * 16;
    union { unsigned short h[16]; uint4 u[2]; } pk;
#pragma unroll
    for (int j = 0; j < 16; ++j) pk.h[j] = TD[er * 68 + dc + j];
    uint4* dst = (uint4*)(MBD + ((long)b * 512 + h * 64 + er) * 512 + h * 64 + dc);
    dst[0] = pk.u[0];
    dst[1] = pk.u[1];
}

// ---------- depthwise 3x3 conv1 + fast GELU, branch-hoisted loads ----------
// y-invalid rows: dummy-safe row pointer + ZEROED WEIGHTS (no per-load select).
// Interior x-tiles (x0 in [16,96]): fully branch-free loads.
__global__ __launch_bounds__(256)
void k_conv1_gelu(const unsigned short* __restrict__ V,
                  const float* __restrict__ w, unsigned short* __restrict__ g) {
    const int x0 = blockIdx.x * 16;
    const int y  = blockIdx.y;
    const int b  = blockIdx.z;
    const int c0 = threadIdx.x * 2;
    const long pixbase = (long)b * 16384;

    const unsigned short* rp[3];
    float w0e[9], w1e[9];
#pragma unroll
    for (int ky = 0; ky < 3; ++ky) {
        const int yy = y + ky - 1;
        const bool ok = (yy >= 0) && (yy < 128);
        rp[ky] = V + (pixbase + (long)(ok ? yy : y) * 128) * 512 + c0;
#pragma unroll
        for (int kx = 0; kx < 3; ++kx) {
            w0e[ky * 3 + kx] = ok ? w[c0 * 9 + ky * 3 + kx] : 0.f;
            w1e[ky * 3 + kx] = ok ? w[(c0 + 1) * 9 + ky * 3 + kx] : 0.f;
        }
    }

    float2 col[3][6];
    if (x0 >= 16 && x0 <= 96) {
        // interior: unconditional loads
#pragma unroll
        for (int ky = 0; ky < 3; ++ky) {
            col[ky][0] = bfpair(*(const unsigned*)(rp[ky] + (long)(x0 - 1) * 512));
            col[ky][1] = bfpair(*(const unsigned*)(rp[ky] + (long)x0 * 512));
        }
        for (int xq = 0; xq < 4; ++xq) {
            const int xb = x0 + xq * 4;
#pragma unroll
            for (int ky = 0; ky < 3; ++ky)
#pragma unroll
                for (int j = 0; j < 4; ++j)
                    col[ky][2 + j] = bfpair(*(const unsigned*)(rp[ky] + (long)(xb + 1 + j) * 512));
#pragma unroll
            for (int j = 0; j < 4; ++j) {
                float a0 = 0.f, a1 = 0.f;
#pragma unroll
                for (int ky = 0; ky < 3; ++ky)
#pragma unroll
                    for (int kx = 0; kx < 3; ++kx) {
                        a0 += col[ky][j + kx].x * w0e[ky * 3 + kx];
                        a1 += col[ky][j + kx].y * w1e[ky * 3 + kx];
                    }
                a0 = gelu_tanh(a0);
                a1 = gelu_tanh(a1);
                *(unsigned*)(g + (pixbase + (long)y * 128 + xb + j) * 512 + c0) =
                    (unsigned)f2bf(a0) | ((unsigned)f2bf(a1) << 16);
            }
#pragma unroll
            for (int ky = 0; ky < 3; ++ky) { col[ky][0] = col[ky][4]; col[ky][1] = col[ky][5]; }
        }
    } else {
        // border: x-checked loads (y handled by zeroed weights)
        auto ldx = [&](int ky, int xx) -> float2 {
            if (xx < 0 || xx > 127) return make_float2(0.f, 0.f);
            return bfpair(*(const unsigned*)(rp[ky] + (long)xx * 512));
        };
#pragma unroll
        for (int ky = 0; ky < 3; ++ky) {
            col[ky][0] = ldx(ky, x0 - 1);
            col[ky][1] = ldx(ky, x0);
        }
        for (int xq = 0; xq < 4; ++xq) {
            const int xb = x0 + xq * 4;
#pragma unroll
            for (int ky = 0; ky < 3; ++ky)
#pragma unroll
                for (int j = 0; j < 4; ++j)
                    col[ky][2 + j] = ldx(ky, xb + 1 + j);
#pragma unroll
            for (int j = 0; j < 4; ++j) {
                float a0 = 0.f, a1 = 0.f;
#pragma unroll
                for (int ky = 0; ky < 3; ++ky)
#pragma unroll
                    for (int kx = 0; kx < 3; ++kx) {
                        a0 += col[ky][j + kx].x * w0e[ky * 3 + kx];
                        a1 += col[ky][j + kx].y * w1e[ky * 3 + kx];
                    }
                a0 = gelu_tanh(a0);
                a1 = gelu_tanh(a1);
                *(unsigned*)(g + (pixbase + (long)y * 128 + xb + j) * 512 + c0) =
                    (unsigned)f2bf(a0) | ((unsigned)f2bf(a1) << 16);
            }
#pragma unroll
            for (int ky = 0; ky < 3; ++ky) { col[ky][0] = col[ky][4]; col[ky][1] = col[ky][5]; }
        }
    }
}

// ---------- conv2: bf16 in -> bf16 out, branch-hoisted ----------
__global__ __launch_bounds__(256)
void k_conv2_bf(const unsigned short* __restrict__ gin,
                const float* __restrict__ w, unsigned short* __restrict__ outbf) {
    const int x0 = blockIdx.x * 16;
    const int y  = blockIdx.y;
    const int b  = blockIdx.z;
    const int c0 = threadIdx.x * 2;
    const long pixbase = (long)b * 16384;

    const unsigned short* rp[3];
    float w0e[9], w1e[9];
#pragma unroll
    for (int ky = 0; ky < 3; ++ky) {
        const int yy = y + ky - 1;
        const bool ok = (yy >= 0) && (yy < 128);
        rp[ky] = gin + (pixbase + (long)(ok ? yy : y) * 128) * 512 + c0;
#pragma unroll
        for (int kx = 0; kx < 3; ++kx) {
            w0e[ky * 3 + kx] = ok ? w[c0 * 9 + ky * 3 + kx] : 0.f;
            w1e[ky * 3 + kx] = ok ? w[(c0 + 1) * 9 + ky * 3 + kx] : 0.f;
        }
    }

    float2 col[3][6];
    if (x0 >= 16 && x0 <= 96) {
#pragma unroll
        for (int ky = 0; ky < 3; ++ky) {
            col[ky][0] = bfpair(*(const unsigned*)(rp[ky] + (long)(x0 - 1) * 512));
            col[ky][1] = bfpair(*(const unsigned*)(rp[ky] + (long)x0 * 512));
        }
        for (int xq = 0; xq < 4; ++xq) {
            const int xb = x0 + xq * 4;
#pragma unroll
            for (int ky = 0; ky < 3; ++ky)
#pragma unroll
                for (int j = 0; j < 4; ++j)
                    col[ky][2 + j] = bfpair(*(const unsigned*)(rp[ky] + (long)(xb + 1 + j) * 512));
#pragma unroll
            for (int j = 0; j < 4; ++j) {
                float a0 = 0.f, a1 = 0.f;
#pragma unroll
                for (int ky = 0; ky < 3; ++ky)
#pragma unroll
                    for (int kx = 0; kx < 3; ++kx) {
                        a0 += col[ky][j + kx].x * w0e[ky * 3 + kx];
                        a1 += col[ky][j + kx].y * w1e[ky * 3 + kx];
                    }
                *(unsigned*)(outbf + (pixbase + (long)y * 128 + xb + j) * 512 + c0) =
                    (unsigned)f2bf(a0) | ((unsigned)f2bf(a1) << 16);
            }
#pragma unroll
            for (int ky = 0; ky < 3; ++ky) { col[ky][0] = col[ky][4]; col[ky][1] = col[ky][5]; }
        }
    } else {
        auto ldx = [&](int ky, int xx) -> float2 {
            if (xx < 0 || xx > 127) return make_float2(0.f, 0.f);
            return bfpair(*(const unsigned*)(rp[ky] + (long)xx * 512));
        };
#pragma unroll
        for (int ky = 0; ky < 3; ++ky) {
            col[ky][0] = ldx(ky, x0 - 1);
            col[ky][1] = ldx(ky, x0);
        }
        for (int xq = 0; xq < 4; ++xq) {
            const int xb = x0 + xq * 4;
#pragma unroll
            for (int ky = 0; ky < 3; ++ky)
#pragma unroll
                for (int j = 0; j < 4; ++j)
                    col[ky][2 + j] = ldx(ky, xb + 1 + j);
#pragma unroll
            for (int j = 0; j < 4; ++j) {
                float a0 = 0.f, a1 = 0.f;
#pragma unroll
                for (int ky = 0; ky < 3; ++ky)
#pragma unroll
                    for (int kx = 0; kx < 3; ++kx) {
                        a0 += col[ky][j + kx].x * w0e[ky * 3 + kx];
                        a1 += col[ky][j + kx].y * w1e[ky * 3 + kx];
                    }
                *(unsigned*)(outbf + (pixbase + (long)y * 128 + xb + j) * 512 + c0) =
                    (unsigned)f2bf(a0) | ((unsigned)f2bf(a1) << 16);
            }
#pragma unroll
            for (int ky = 0; ky < 3; ++ky) { col[ky][0] = col[ky][4]; col[ky][1] = col[ky][5]; }
        }
    }
}

// ---------- launch ----------
extern "C" void kernel_launch(void* const* d_in, const int* in_sizes, int n_in,
                              void* d_out, int out_size, void* d_ws, size_t ws_size,
                              hipStream_t stream) {
    const float* x_in    = (const float*)d_in[0];
    const float* Wq      = (const float*)d_in[1];
    const float* Wk      = (const float*)d_in[2];
    const float* Wv      = (const float*)d_in[3];
    const float* rescale = (const float*)d_in[4];
    const float* Wp      = (const float*)d_in[5];
    const float* bp      = (const float*)d_in[6];
    const float* c1w     = (const float*)d_in[7];
    const float* c2w     = (const float*)d_in[8];
    float* out = (float*)d_out;

    char* ws = (char*)d_ws;
    unsigned short* XBF = (unsigned short*)(ws);                  // [65536][512] bf16; reused as g buf
    unsigned short* VBF = (unsigned short*)(ws + 67108864LL);     // [65536][512] bf16
    unsigned short* XT  = (unsigned short*)(ws + 134217728LL);    // [4][512][16384] bf16; reused as CV2
    unsigned short* CV2 = XT;                                     // conv2 out bf16 (after gram done)
    float*          P   = (float*)(ws + 201326592LL);             // f32 partials
    unsigned short* WCT = (unsigned short*)(ws + 234881024LL);    // [WqT;WkT;WvT;WpT]
    unsigned short* GB  = (unsigned short*)(ws + 236978176LL);    // [4][512][512] bf16
    unsigned short* T12 = (unsigned short*)(ws + 239075328LL);    // [4][1024][512] bf16 (T1|T2)
    float*          SSQ = (float*)(ws + 243269632LL);
    float*          ATTF= (float*)(ws + 243286016LL);
    unsigned short* MBD = (unsigned short*)(ws + 247480320LL);
    unsigned short* WEF = (unsigned short*)(ws + 249577472LL);

    (void)hipMemsetAsync(MBD, 0, 2097152, stream);

    k_cvt_tr<<<dim3(8, 1024), dim3(256), 0, stream>>>(x_in, XBF, XT);
    k_build_wcat<<<dim3(16, 64), dim3(256), 0, stream>>>(Wq, Wk, Wv, Wp, WCT);

    // V = X @ Wv
    gemm_mfma<1, 0, 0><<<dim3(4, 512, 1), dim3(256), 0, stream>>>(
        XBF, WCT + 2 * 262144, (void*)VBF, nullptr, nullptr, 512, 512, 512, 512, 0L, 0L, 0L);

    // Gram matrix: symmetry-halved split-K
    gemm_gram<<<dim3(10, 32), dim3(256), 0, stream>>>(XT, P);
    k_greduce<<<dim3(2048), dim3(256), 0, stream>>>(P, (unsigned*)GB);

    // merged sandwich: T12[b] = [WqT;WkT] x GB[b]^T  (M=1024)
    gemm_mfma<1, 0, 0><<<dim3(4, 8, 4), dim3(256), 0, stream>>>(
        WCT, GB, (void*)T12, nullptr, nullptr, 512, 512, 512, 512, 0L, 262144L, 524288L);
    // attn = T2 x WqT^T  (T2 = T12 rows 512..1023)
    gemm_mfma<0, 0, 0><<<dim3(4, 4, 4), dim3(256), 0, stream>>>(
        T12 + 262144, WCT, (void*)ATTF, nullptr, nullptr, 512, 512, 512, 512, 524288L, 0L, 262144L);

    k_ssq<<<dim3(4, 4), dim3(256), 0, stream>>>(WCT, T12, SSQ);
    k_softmax_bd<<<dim3(32), dim3(256), 0, stream>>>(ATTF, SSQ, rescale, MBD);

    // Weff^T[b] = WpT x MBD[b]^T
    gemm_mfma<1, 0, 0><<<dim3(4, 4, 4), dim3(256), 0, stream>>>(
        WCT + 3 * 262144, MBD, (void*)WEF, nullptr, nullptr, 512, 512, 512, 512, 0L, 262144L, 262144L);

    // positional branch: split conv1 -> g (XBF), conv2 -> CV2 (bf16)
    k_conv1_gelu<<<dim3(8, 128, 4), dim3(256), 0, stream>>>(VBF, c1w, XBF);
    k_conv2_bf<<<dim3(8, 128, 4), dim3(256), 0, stream>>>(XBF, c2w, CV2);

    // out = V @ Weff^T + bp + CV2
    gemm_mfma<0, 1, 1><<<dim3(4, 128, 4), dim3(256), 0, stream>>>(
        VBF, WEF, (void*)out, bp, CV2, 512, 512, 512, 512,
        (long)16384 * 512, 262144L, (long)16384 * 512);
}

// Round 17
// 385.858 us; speedup vs baseline: 1.0786x; 1.0786x over previous
//
#include <hip/hip_runtime.h>
#include <hip/hip_bf16.h>

// ---------- types & helpers ----------
typedef __attribute__((ext_vector_type(4))) float f32x4;
typedef __attribute__((ext_vector_type(8))) short s16x8;

__device__ __forceinline__ unsigned short f2bf(float f) {
    __hip_bfloat16 h = __float2bfloat16(f);
    return __builtin_bit_cast(unsigned short, h);
}
__device__ __forceinline__ float bf2f(unsigned short u) {
    return __builtin_bit_cast(float, ((unsigned)u) << 16);
}
__device__ __forceinline__ float2 bfpair(unsigned u) {
    float2 r;
    r.x = __builtin_bit_cast(float, u << 16);
    r.y = __builtin_bit_cast(float, u & 0xffff0000u);
    return r;
}
__device__ __forceinline__ void gload_lds16(const void* g, void* l) {
    __builtin_amdgcn_global_load_lds(
        (const __attribute__((address_space(1))) void*)g,
        (__attribute__((address_space(3))) void*)l, 16, 0, 0);
}
__device__ __forceinline__ float gelu_tanh(float x) {
    const float y = 0.7978845608028654f * (x + 0.044715f * x * x * x);
    const float t = __expf(-2.f * fabsf(y));
    const float th = (1.f - t) / (1.f + t);
    return 0.5f * x * (1.f + copysignf(th, y));
}

// ---------- fused fp32->bf16 convert + transpose ----------
// LDS swizzle uses ((c>>2)&7) = cq&7 so the 16 cq-lanes of each store spread
// over 8 XOR values (4-way conflict) instead of 2 (16-way) [R16 post-mortem].
__global__ __launch_bounds__(256)
void k_cvt_tr(const float* __restrict__ in, unsigned short* __restrict__ XBF,
              unsigned short* __restrict__ XT) {
    __shared__ __align__(16) unsigned short tile[64 * 64];
    const int t  = threadIdx.x;
    const int c0 = blockIdx.x * 64;
    const int ty = blockIdx.y;
    const long tokg = (long)ty * 64;
    const int cq = t & 15, r0 = t >> 4;
#pragma unroll
    for (int p = 0; p < 4; ++p) {
        const int tok = r0 + p * 16;
        const float4 v = *(const float4*)(in + (tokg + tok) * 512 + c0 + cq * 4);
        union { unsigned short h[4]; uint2 u; } pk;
        pk.h[0] = f2bf(v.x); pk.h[1] = f2bf(v.y); pk.h[2] = f2bf(v.z); pk.h[3] = f2bf(v.w);
        *(uint2*)(XBF + (tokg + tok) * 512 + c0 + cq * 4) = pk.u;
        const int T = tok >> 3, i = tok & 7;
#pragma unroll
        for (int j = 0; j < 4; ++j) {
            const int c = cq * 4 + j;
            tile[c * 64 + ((T ^ ((c >> 2) & 7)) * 8 + i)] = pk.h[j];
        }
    }
    __syncthreads();
    const int b  = ty >> 8;
    const long tb = (long)(ty & 255) * 64;
    const int T2 = t & 7;
#pragma unroll
    for (int q = 0; q < 2; ++q) {
        const int c = (t >> 3) + q * 32;
        const uint4 v = *(const uint4*)&tile[c * 64 + ((T2 ^ ((c >> 2) & 7)) * 8)];
        *(uint4*)(XT + ((long)(b * 512 + c0 + c)) * 16384 + tb + T2 * 8) = v;
    }
}

// ---------- build [WqT; WkT; WvT; WpT] bf16 [2048][512] via LDS 32x32 transpose ----------
__global__ __launch_bounds__(256)
void k_build_wcat(const float* __restrict__ Wq, const float* __restrict__ Wk,
                  const float* __restrict__ Wv, const float* __restrict__ Wp,
                  unsigned short* __restrict__ WcatT) {
    __shared__ float t[32][33];
    const int k0 = blockIdx.x * 32;
    const int j0 = blockIdx.y * 32;
    const float* src = (j0 < 512) ? Wq : (j0 < 1024 ? Wk : (j0 < 1536 ? Wv : Wp));
    const int jc0 = j0 & 511;
    const int r = threadIdx.x >> 5, c = threadIdx.x & 31;
#pragma unroll
    for (int rr = 0; rr < 4; ++rr) {
        const int k = k0 + r + rr * 8;
        t[c][r + rr * 8] = src[(long)k * 512 + jc0 + c];
    }
    __syncthreads();
#pragma unroll
    for (int rr = 0; rr < 4; ++rr) {
        const int j = j0 + r + rr * 8;
        WcatT[(long)j * 512 + k0 + c] = f2bf(t[r + rr * 8][c]);
    }
}

// ---------- MFMA bf16 GEMM 128x128 (m97-style): C[M,N] = A[M,K] * B[N,K]^T ----------
#define BM 128
#define BN 128
#define BK 64

template<int OUT_BF16, int BIAS, int ADDC>
__global__ __launch_bounds__(256, 4)
void gemm_mfma(const unsigned short* __restrict__ A, const unsigned short* __restrict__ B,
               void* __restrict__ C_, const float* __restrict__ bias,
               const unsigned short* __restrict__ addc,
               int lda, int ldb, int ldc, int K, long sA, long sB, long sC) {
    __shared__ __align__(16) unsigned short sm[BM * BK * 2];   // As | Bs; reused as C staging
    unsigned short* As = sm;
    unsigned short* Bs = sm + BM * BK;

    const int tid  = threadIdx.x;
    const int wave = tid >> 6;
    const int lane = tid & 63;
    const int wm = wave >> 1, wn = wave & 1;

    // XCD swizzle: consecutive-on-XCD blocks share the A panel
    const int nx = gridDim.x, ny = gridDim.y;
    const int nwg = nx * ny * gridDim.z;
    int lid = blockIdx.x + nx * (blockIdx.y + ny * blockIdx.z);
    lid = (lid & 7) * (nwg >> 3) + (lid >> 3);
    const int bxi = lid % nx;
    const int rest = lid / nx;
    const int byi = rest % ny;
    const long bz = rest / ny;
    const int bm0 = byi * BM;
    const int bn0 = bxi * BN;
    A += bz * sA;
    B += bz * sB;

    const int l15 = lane & 15;
    const int l4  = lane >> 4;

    f32x4 acc[4][4];
#pragma unroll
    for (int i = 0; i < 4; ++i)
#pragma unroll
        for (int j = 0; j < 4; ++j) acc[i][j] = (f32x4){0.f, 0.f, 0.f, 0.f};

    const int srow    = wave * 8 + (lane >> 3);
    const int schunk0 = lane & 7;
    const int arow_b  = wm * 64 + l15;
    const int brow_b  = wn * 64 + l15;

    const int nk = K / BK;
    for (int kt = 0; kt < nk; ++kt) {
        const int k0 = kt * BK;
#pragma unroll
        for (int i = 0; i < 4; ++i) {
            const int r  = i * 32 + srow;
            const int gc = schunk0 ^ (r & 7);
            gload_lds16(A + (long)(bm0 + r) * lda + (k0 + gc * 8), &As[(i * 32 + wave * 8) * BK]);
            gload_lds16(B + (long)(bn0 + r) * ldb + (k0 + gc * 8), &Bs[(i * 32 + wave * 8) * BK]);
        }
        __syncthreads();
        s16x8 af[4][2], bfr[4][2];
#pragma unroll
        for (int mi = 0; mi < 4; ++mi) {
            const int row = arow_b + mi * 16;
#pragma unroll
            for (int ki = 0; ki < 2; ++ki) {
                const int ch = (ki * 4 + l4) ^ (row & 7);
                af[mi][ki] = *(const s16x8*)&As[row * BK + ch * 8];
            }
        }
#pragma unroll
        for (int ni = 0; ni < 4; ++ni) {
            const int row = brow_b + ni * 16;
#pragma unroll
            for (int ki = 0; ki < 2; ++ki) {
                const int ch = (ki * 4 + l4) ^ (row & 7);
                bfr[ni][ki] = *(const s16x8*)&Bs[row * BK + ch * 8];
            }
        }
#pragma unroll
        for (int ki = 0; ki < 2; ++ki)
#pragma unroll
            for (int mi = 0; mi < 4; ++mi)
#pragma unroll
                for (int ni = 0; ni < 4; ++ni)
                    acc[mi][ni] = __builtin_amdgcn_mfma_f32_16x16x32_bf16(
                        af[mi][ki], bfr[ni][ki], acc[mi][ni], 0, 0, 0);
        __syncthreads();
    }

    // ---- staged epilogue: acc -> LDS -> wide coalesced stores ----
    if (OUT_BF16) {
        unsigned short* Cs = sm;   // [128][64] bf16 (16KB)
        unsigned short* C = (unsigned short*)C_ + bz * sC;
#pragma unroll
        for (int pass = 0; pass < 2; ++pass) {
            __syncthreads();
            if (wn == pass) {
#pragma unroll
                for (int mi = 0; mi < 4; ++mi)
#pragma unroll
                    for (int ni = 0; ni < 4; ++ni)
#pragma unroll
                        for (int j = 0; j < 4; ++j)
                            Cs[(wm * 64 + mi * 16 + l4 * 4 + j) * 64 + ni * 16 + l15] =
                                f2bf(acc[mi][ni][j]);
            }
            __syncthreads();
            const int colL = (tid & 7) * 8;
#pragma unroll
            for (int it = 0; it < 4; ++it) {
                const int row = it * 32 + (tid >> 3);
                const uint4 v = *(const uint4*)&Cs[row * 64 + colL];
                *(uint4*)&C[(long)(bm0 + row) * ldc + bn0 + pass * 64 + colL] = v;
            }
        }
    } else {
        float* Cs = (float*)sm;    // [128][64] f32 (32KB)
        float* C = (float*)C_ + bz * sC;
#pragma unroll
        for (int pass = 0; pass < 2; ++pass) {
            __syncthreads();
            if (wn == pass) {
#pragma unroll
                for (int mi = 0; mi < 4; ++mi)
#pragma unroll
                    for (int ni = 0; ni < 4; ++ni)
#pragma unroll
                        for (int j = 0; j < 4; ++j)
                            Cs[(wm * 64 + mi * 16 + l4 * 4 + j) * 64 + ni * 16 + l15] =
                                acc[mi][ni][j];
            }
            __syncthreads();
            const int colL = (tid & 15) * 4;
#pragma unroll
            for (int it = 0; it < 8; ++it) {
                const int row = it * 16 + (tid >> 4);
                f32x4 v = *(const f32x4*)&Cs[row * 64 + colL];
                const long gr = bm0 + row;
                const int gc = bn0 + pass * 64 + colL;
                if (BIAS) {
                    const float4 bv = *(const float4*)(bias + gc);
                    v[0] += bv.x; v[1] += bv.y; v[2] += bv.z; v[3] += bv.w;
                }
                if (ADDC) {
                    const uint2 a2 = *(const uint2*)(addc + bz * sC + gr * ldc + gc);
                    v[0] += bf2f((unsigned short)(a2.x & 0xffff));
                    v[1] += bf2f((unsigned short)(a2.x >> 16));
                    v[2] += bf2f((unsigned short)(a2.y & 0xffff));
                    v[3] += bf2f((unsigned short)(a2.y >> 16));
                }
                *(f32x4*)&C[gr * ldc + gc] = v;
            }
        }
    }
}

// ---------- Gram split-K, SYMMETRY-HALVED ----------
__global__ __launch_bounds__(256, 4)
void gemm_gram(const unsigned short* __restrict__ XT, float* __restrict__ P) {
    __shared__ __align__(16) unsigned short As[128 * 64];
    __shared__ __align__(16) unsigned short Bs[128 * 64];
    const int tid = threadIdx.x, wave = tid >> 6, lane = tid & 63;
    const int wm = wave >> 1, wn = wave & 1;
    const int p = blockIdx.x;               // 0..9
    int ti, tj;
    if (p < 4)      { ti = 0; tj = p; }
    else if (p < 7) { ti = 1; tj = p - 3; }
    else if (p < 9) { ti = 2; tj = p - 5; }
    else            { ti = 3; tj = 3; }
    const int bm0 = ti * 128, bn0 = tj * 128;
    const int z = blockIdx.y, b = z >> 3, chunk = z & 7;
    const unsigned short* A = XT + (long)b * 512 * 16384;
    const int l15 = lane & 15, l4 = lane >> 4;

    f32x4 acc[4][4];
#pragma unroll
    for (int i = 0; i < 4; ++i)
#pragma unroll
        for (int j = 0; j < 4; ++j) acc[i][j] = (f32x4){0.f, 0.f, 0.f, 0.f};

    const int srow = wave * 8 + (lane >> 3);
    const int sch  = lane & 7;
    const int arow_b = wm * 64 + l15;
    const int brow_b = wn * 64 + l15;

    for (int kt = 0; kt < 32; ++kt) {
        const long k0 = (long)chunk * 2048 + kt * 64;
#pragma unroll
        for (int i = 0; i < 4; ++i) {
            const int r  = i * 32 + srow;
            const int gc = sch ^ (r & 7);
            gload_lds16(A + (long)(bm0 + r) * 16384 + k0 + gc * 8, &As[(i * 32 + wave * 8) * 64]);
            gload_lds16(A + (long)(bn0 + r) * 16384 + k0 + gc * 8, &Bs[(i * 32 + wave * 8) * 64]);
        }
        __syncthreads();
        s16x8 af[4][2], bfr[4][2];
#pragma unroll
        for (int mi = 0; mi < 4; ++mi) {
            const int row = arow_b + mi * 16;
#pragma unroll
            for (int ki = 0; ki < 2; ++ki)
                af[mi][ki] = *(const s16x8*)&As[row * 64 + (((ki * 4 + l4) ^ (row & 7))) * 8];
        }
#pragma unroll
        for (int ni = 0; ni < 4; ++ni) {
            const int row = brow_b + ni * 16;
#pragma unroll
            for (int ki = 0; ki < 2; ++ki)
                bfr[ni][ki] = *(const s16x8*)&Bs[row * 64 + (((ki * 4 + l4) ^ (row & 7))) * 8];
        }
#pragma unroll
        for (int ki = 0; ki < 2; ++ki)
#pragma unroll
            for (int mi = 0; mi < 4; ++mi)
#pragma unroll
                for (int ni = 0; ni < 4; ++ni)
                    acc[mi][ni] = __builtin_amdgcn_mfma_f32_16x16x32_bf16(
                        af[mi][ki], bfr[ni][ki], acc[mi][ni], 0, 0, 0);
        __syncthreads();
    }

    const long zbase = (long)(b * 8 + chunk) * 16;
    float* Pb = P + (zbase + ti * 4 + tj) * 16384;
#pragma unroll
    for (int mi = 0; mi < 4; ++mi) {
        const int row0 = wm * 64 + mi * 16 + l4 * 4;
#pragma unroll
        for (int ni = 0; ni < 4; ++ni) {
            const int col = wn * 64 + ni * 16 + l15;
#pragma unroll
            for (int j = 0; j < 4; ++j)
                Pb[(row0 + j) * 128 + col] = acc[mi][ni][j];
        }
    }
    if (ti != tj) {   // mirror block
        float* Pt = P + (zbase + tj * 4 + ti) * 16384;
#pragma unroll
        for (int mi = 0; mi < 4; ++mi) {
            const int row0 = wm * 64 + mi * 16 + l4 * 4;
#pragma unroll
            for (int ni = 0; ni < 4; ++ni) {
                const int col = wn * 64 + ni * 16 + l15;
                *(f32x4*)&Pt[(long)col * 128 + row0] = acc[mi][ni];
            }
        }
    }
}

// ---------- reduce partials over chunks -> GB bf16 [4][512][512] ----------
__global__ void k_greduce(const float* __restrict__ P, unsigned* __restrict__ GB2) {
    const long idx = (long)blockIdx.x * 256 + threadIdx.x;
    const int b   = (int)(idx >> 17);
    const int rem = (int)(idx & 131071);
    const int c   = rem >> 8;
    const int cp0 = (rem & 255) * 2;
    const int tp  = (c >> 7) * 4 + (cp0 >> 7);
    const int e   = (c & 127) * 128 + (cp0 & 127);
    const float* Pp = P + ((long)(b * 8) * 16 + tp) * 16384 + e;
    float s0 = 0.f, s1 = 0.f;
#pragma unroll
    for (int ch = 0; ch < 8; ++ch) {
        const float2 v = *(const float2*)(Pp + (long)ch * 16 * 16384);
        s0 += v.x; s1 += v.y;
    }
    GB2[idx] = (unsigned)f2bf(s0) | ((unsigned)f2bf(s1) << 16);
}

// ---------- row-dots for sumsq (T12 layout: [b][1024][512]) ----------
__global__ void k_ssq(const unsigned short* __restrict__ WCT, const unsigned short* __restrict__ T12,
                      float* __restrict__ SSQ) {
    const int b = blockIdx.y;
    const int o = blockIdx.x * 256 + threadIdx.x;   // 0..1023
    const unsigned short* wrow = WCT + (long)o * 512;
    const unsigned short* trow = T12 + (long)b * 524288 + (long)o * 512;
    float s = 0.f;
    for (int c = 0; c < 512; c += 8) {
        const s16x8 w = *(const s16x8*)&wrow[c];
        const s16x8 v = *(const s16x8*)&trow[c];
#pragma unroll
        for (int j = 0; j < 8; ++j)
            s += bf2f((unsigned short)w[j]) * bf2f((unsigned short)v[j]);
    }
    SSQ[b * 1024 + o] = s;
}

// ---------- softmax -> block-diagonal bf16 matrix MBD[b][h*64+e][h*64+d] ----------
__global__ __launch_bounds__(256)
void k_softmax_bd(const float* __restrict__ attn, const float* __restrict__ sumsq,
                  const float* __restrict__ rescale, unsigned short* __restrict__ MBD) {
    __shared__ unsigned short TD[64 * 68];
    const int bh = blockIdx.x;
    const int b = bh >> 3, h = bh & 7;
    const int wave = threadIdx.x >> 6, e = threadIdx.x & 63;
    const float rs   = rescale[h];
    const float invq = rsqrtf(sumsq[b * 1024 + h * 64 + e]);
#pragma unroll 4
    for (int i = 0; i < 16; ++i) {
        const int d = wave * 16 + i;
        const float invk = rsqrtf(sumsq[b * 1024 + 512 + h * 64 + d]);
        const float v = attn[((long)b * 512 + h * 64 + d) * 512 + h * 64 + e] * invk * invq * rs;
        float mx = v;
#pragma unroll
        for (int off = 32; off >= 1; off >>= 1) mx = fmaxf(mx, __shfl_xor(mx, off));
        const float l = __expf(v - mx);
        float s = l;
#pragma unroll
        for (int off = 32; off >= 1; off >>= 1) s += __shfl_xor(s, off);
        TD[e * 68 + d] = f2bf(l / s);
    }
    __syncthreads();
    const int er = threadIdx.x >> 2, dc = (threadIdx.x & 3) * 16;
    union { unsigned short h[16]; uint4 u[2]; } pk;
#pragma unroll
    for (int j = 0; j < 16; ++j) pk.h[j] = TD[er * 68 + dc + j];
    uint4* dst = (uint4*)(MBD + ((long)b * 512 + h * 64 + er) * 512 + h * 64 + dc);
    dst[0] = pk.u[0];
    dst[1] = pk.u[1];
}

// ---------- depthwise 3x3 conv1 + fast GELU, x-unrolled x4 (R13 proven form) ----------
__global__ __launch_bounds__(256)
void k_conv1_gelu(const unsigned short* __restrict__ V,   // pixel stride 512
                  const float* __restrict__ w, unsigned short* __restrict__ g) {
    const int x0 = blockIdx.x * 16;
    const int y  = blockIdx.y;
    const int b  = blockIdx.z;
    const int c0 = threadIdx.x * 2;
    float wq0[9], wq1[9];
#pragma unroll
    for (int i = 0; i < 9; ++i) { wq0[i] = w[c0 * 9 + i]; wq1[i] = w[(c0 + 1) * 9 + i]; }
    const long pixbase = (long)b * 16384;

    auto ld = [&](int yy, int xx) -> float2 {
        if (yy < 0 || yy > 127 || xx < 0 || xx > 127) return make_float2(0.f, 0.f);
        return bfpair(*(const unsigned*)(V + (pixbase + (long)yy * 128 + xx) * 512 + c0));
    };

    float2 col[3][6];
#pragma unroll
    for (int ky = 0; ky < 3; ++ky) {
        col[ky][0] = ld(y + ky - 1, x0 - 1);
        col[ky][1] = ld(y + ky - 1, x0);
    }
    for (int xq = 0; xq < 4; ++xq) {
        const int xb = x0 + xq * 4;
#pragma unroll
        for (int ky = 0; ky < 3; ++ky)
#pragma unroll
            for (int j = 0; j < 4; ++j)
                col[ky][2 + j] = ld(y + ky - 1, xb + 1 + j);
#pragma unroll
        for (int j = 0; j < 4; ++j) {
            float a0 = 0.f, a1 = 0.f;
#pragma unroll
            for (int ky = 0; ky < 3; ++ky)
#pragma unroll
                for (int kx = 0; kx < 3; ++kx) {
                    a0 += col[ky][j + kx].x * wq0[ky * 3 + kx];
                    a1 += col[ky][j + kx].y * wq1[ky * 3 + kx];
                }
            a0 = gelu_tanh(a0);
            a1 = gelu_tanh(a1);
            const unsigned up = (unsigned)f2bf(a0) | ((unsigned)f2bf(a1) << 16);
            *(unsigned*)(g + (pixbase + (long)y * 128 + xb + j) * 512 + c0) = up;
        }
#pragma unroll
        for (int ky = 0; ky < 3; ++ky) {
            col[ky][0] = col[ky][4];
            col[ky][1] = col[ky][5];
        }
    }
}

// ---------- conv2: bf16 in -> bf16 out (R13 proven form) ----------
__global__ __launch_bounds__(256)
void k_conv2_bf(const unsigned short* __restrict__ gin,
                const float* __restrict__ w, unsigned short* __restrict__ outbf) {
    const int x0 = blockIdx.x * 16;
    const int y  = blockIdx.y;
    const int b  = blockIdx.z;
    const int c0 = threadIdx.x * 2;
    float wq0[9], wq1[9];
#pragma unroll
    for (int i = 0; i < 9; ++i) { wq0[i] = w[c0 * 9 + i]; wq1[i] = w[(c0 + 1) * 9 + i]; }
    const long pixbase = (long)b * 16384;

    auto ld = [&](int yy, int xx) -> float2 {
        if (yy < 0 || yy > 127 || xx < 0 || xx > 127) return make_float2(0.f, 0.f);
        return bfpair(*(const unsigned*)(gin + (pixbase + (long)yy * 128 + xx) * 512 + c0));
    };

    float2 col[3][6];
#pragma unroll
    for (int ky = 0; ky < 3; ++ky) {
        col[ky][0] = ld(y + ky - 1, x0 - 1);
        col[ky][1] = ld(y + ky - 1, x0);
    }
    for (int xq = 0; xq < 4; ++xq) {
        const int xb = x0 + xq * 4;
#pragma unroll
        for (int ky = 0; ky < 3; ++ky)
#pragma unroll
            for (int j = 0; j < 4; ++j)
                col[ky][2 + j] = ld(y + ky - 1, xb + 1 + j);
#pragma unroll
        for (int j = 0; j < 4; ++j) {
            float a0 = 0.f, a1 = 0.f;
#pragma unroll
            for (int ky = 0; ky < 3; ++ky)
#pragma unroll
                for (int kx = 0; kx < 3; ++kx) {
                    a0 += col[ky][j + kx].x * wq0[ky * 3 + kx];
                    a1 += col[ky][j + kx].y * wq1[ky * 3 + kx];
                }
            const unsigned up = (unsigned)f2bf(a0) | ((unsigned)f2bf(a1) << 16);
            *(unsigned*)(outbf + (pixbase + (long)y * 128 + xb + j) * 512 + c0) = up;
        }
#pragma unroll
        for (int ky = 0; ky < 3; ++ky) {
            col[ky][0] = col[ky][4];
            col[ky][1] = col[ky][5];
        }
    }
}

// ---------- launch ----------
extern "C" void kernel_launch(void* const* d_in, const int* in_sizes, int n_in,
                              void* d_out, int out_size, void* d_ws, size_t ws_size,
                              hipStream_t stream) {
    const float* x_in    = (const float*)d_in[0];
    const float* Wq      = (const float*)d_in[1];
    const float* Wk      = (const float*)d_in[2];
    const float* Wv      = (const float*)d_in[3];
    const float* rescale = (const float*)d_in[4];
    const float* Wp      = (const float*)d_in[5];
    const float* bp      = (const float*)d_in[6];
    const float* c1w     = (const float*)d_in[7];
    const float* c2w     = (const float*)d_in[8];
    float* out = (float*)d_out;

    char* ws = (char*)d_ws;
    unsigned short* XBF = (unsigned short*)(ws);                  // [65536][512] bf16; reused as g buf
    unsigned short* VBF = (unsigned short*)(ws + 67108864LL);     // [65536][512] bf16
    unsigned short* XT  = (unsigned short*)(ws + 134217728LL);    // [4][512][16384] bf16; reused as CV2
    unsigned short* CV2 = XT;                                     // conv2 out bf16 (after gram done)
    float*          P   = (float*)(ws + 201326592LL);             // f32 partials
    unsigned short* WCT = (unsigned short*)(ws + 234881024LL);    // [WqT;WkT;WvT;WpT]
    unsigned short* GB  = (unsigned short*)(ws + 236978176LL);    // [4][512][512] bf16
    unsigned short* T12 = (unsigned short*)(ws + 239075328LL);    // [4][1024][512] bf16 (T1|T2)
    float*          SSQ = (float*)(ws + 243269632LL);
    float*          ATTF= (float*)(ws + 243286016LL);
    unsigned short* MBD = (unsigned short*)(ws + 247480320LL);
    unsigned short* WEF = (unsigned short*)(ws + 249577472LL);

    (void)hipMemsetAsync(MBD, 0, 2097152, stream);

    k_cvt_tr<<<dim3(8, 1024), dim3(256), 0, stream>>>(x_in, XBF, XT);
    k_build_wcat<<<dim3(16, 64), dim3(256), 0, stream>>>(Wq, Wk, Wv, Wp, WCT);

    // V = X @ Wv
    gemm_mfma<1, 0, 0><<<dim3(4, 512, 1), dim3(256), 0, stream>>>(
        XBF, WCT + 2 * 262144, (void*)VBF, nullptr, nullptr, 512, 512, 512, 512, 0L, 0L, 0L);

    // Gram matrix: symmetry-halved split-K
    gemm_gram<<<dim3(10, 32), dim3(256), 0, stream>>>(XT, P);
    k_greduce<<<dim3(2048), dim3(256), 0, stream>>>(P, (unsigned*)GB);

    // merged sandwich: T12[b] = [WqT;WkT] x GB[b]^T  (M=1024)
    gemm_mfma<1, 0, 0><<<dim3(4, 8, 4), dim3(256), 0, stream>>>(
        WCT, GB, (void*)T12, nullptr, nullptr, 512, 512, 512, 512, 0L, 262144L, 524288L);
    // attn = T2 x WqT^T  (T2 = T12 rows 512..1023)
    gemm_mfma<0, 0, 0><<<dim3(4, 4, 4), dim3(256), 0, stream>>>(
        T12 + 262144, WCT, (void*)ATTF, nullptr, nullptr, 512, 512, 512, 512, 524288L, 0L, 262144L);

    k_ssq<<<dim3(4, 4), dim3(256), 0, stream>>>(WCT, T12, SSQ);
    k_softmax_bd<<<dim3(32), dim3(256), 0, stream>>>(ATTF, SSQ, rescale, MBD);

    // Weff^T[b] = WpT x MBD[b]^T
    gemm_mfma<1, 0, 0><<<dim3(4, 4, 4), dim3(256), 0, stream>>>(
        WCT + 3 * 262144, MBD, (void*)WEF, nullptr, nullptr, 512, 512, 512, 512, 0L, 262144L, 262144L);

    // positional branch: split conv1 -> g (XBF), conv2 -> CV2 (bf16)
    k_conv1_gelu<<<dim3(8, 128, 4), dim3(256), 0, stream>>>(VBF, c1w, XBF);
    k_conv2_bf<<<dim3(8, 128, 4), dim3(256), 0, stream>>>(XBF, c2w, CV2);

    // out = V @ Weff^T + bp + CV2
    gemm_mfma<0, 1, 1><<<dim3(4, 128, 4), dim3(256), 0, stream>>>(
        VBF, WEF, (void*)out, bp, CV2, 512, 512, 512, 512,
        (long)16384 * 512, 262144L, (long)16384 * 512);
}